// Round 4
// baseline (198.271 us; speedup 1.0000x reference)
//
#include <hip/hip_runtime.h>

#define BB 32
#define PP 32768
#define CC 81
#define RPB 64    // rows (priors) per block in K1
#define TPB 256

// ws layout (bytes):
//   0:    double neg_acc
//   8:    double d_ll[32]
//   264:  double d_ce[32]
//   520:  double d_msum[32]
//   776:  int    num_pos[32]
//   904:  int    nnz[32]
//   2048: float  mine[B*P]  (4 MB)

__device__ __forceinline__ float sl1f(float d) {
    float ad = fabsf(d);
    return ad < 1.f ? 0.5f * d * d : ad - 0.5f;
}

__global__ __launch_bounds__(TPB) void ce_loc_kernel(
    const float* __restrict__ conf, const int* __restrict__ labels,
    const float* __restrict__ locd, const float* __restrict__ loct,
    float* __restrict__ mine, double* __restrict__ d_ll, double* __restrict__ d_ce,
    double* __restrict__ d_msum, int* __restrict__ num_pos, int* __restrict__ nnz)
{
    __shared__ float ex[RPB * CC];          // 5184 floats = 20736 B -> 7 blocks/CU

    const int t = threadIdx.x;
    const size_t gp0 = (size_t)blockIdx.x * RPB;

    // ---- phase 1: pure stream. 1296 float4, lane-consecutive (m13 pattern),
    //      exp element-wise, deposit to LDS. 16B-aligned (block byte offset 20736).
    const float4* __restrict__ src = (const float4*)(conf + gp0 * CC);
    float4* dst = (float4*)ex;
#pragma unroll
    for (int i = 0; i < 5; ++i) {
        float4 v = src[t + i * TPB];
        v.x = __expf(v.x); v.y = __expf(v.y);
        v.z = __expf(v.z); v.w = __expf(v.w);
        dst[t + i * TPB] = v;
    }
    if (t < 16) {
        float4 v = src[1280 + t];
        v.x = __expf(v.x); v.y = __expf(v.y);
        v.z = __expf(v.z); v.w = __expf(v.w);
        dst[1280 + t] = v;
    }
    __syncthreads();

    // ---- phase 2: wave 0, one thread per row ----
    if (t < RPB) {
        const size_t gp = gp0 + t;
        const int b = (int)(blockIdx.x >> 9);     // 512 blocks per batch row
        const int lab = labels[gp];               // coalesced 256B
        const float* row = ex + t * CC;           // LDS banks (17t+c)%32: 2-way, free

        float s0 = 0.f, s1 = 0.f, s2 = 0.f, s3 = 0.f;
#pragma unroll
        for (int c = 0; c < 20; ++c) {
            s0 += row[4 * c];     s1 += row[4 * c + 1];
            s2 += row[4 * c + 2]; s3 += row[4 * c + 3];
        }
        s0 += row[80];
        const float s = (s0 + s1) + (s2 + s3);
        const float exl = row[lab];               // exp(x[label]) > 0 for this data
        const float ce = __logf(__fdividef(s, exl));   // log(sum) - x[label]
        const bool pos = lab > 0;

        const float4 a  = ((const float4*)locd)[gp];   // aligned, coalesced
        const float4 bt = ((const float4*)loct)[gp];
        float ll = 0.f;
        if (pos) ll = sl1f(a.x - bt.x) + sl1f(a.y - bt.y)
                    + sl1f(a.z - bt.z) + sl1f(a.w - bt.w);

        float pce = 0.f, pcf = 0.f, mval = 0.f, nnzf = 0.f;
        if (pos) { pce = ce; pcf = 1.f; }
        else {
            mval = fmaxf(ce, 0.f);                // clamp: uint-monotone radix keys
            nnzf = (mval > 0.f) ? 1.f : 0.f;
        }
        mine[gp] = mval;                          // coalesced 256B store

        // wave-64 reduce (t<64 == wave 0 exactly)
#pragma unroll
        for (int off = 32; off; off >>= 1) {
            ll   += __shfl_down(ll, off);
            pce  += __shfl_down(pce, off);
            pcf  += __shfl_down(pcf, off);
            mval += __shfl_down(mval, off);
            nnzf += __shfl_down(nnzf, off);
        }
        if (t == 0) {
            atomicAdd(&d_ll[b], (double)ll);
            atomicAdd(&d_ce[b], (double)pce);
            atomicAdd(&d_msum[b], (double)mval);
            atomicAdd(&num_pos[b], (int)pcf);
            atomicAdd(&nnz[b], (int)nnzf);
        }
    }
}

// Per-row top-k sum. Fast path: k >= nnz => answer is msum[b]. General inputs
// fall back to radix select on float bits (keys >= 0, uint-monotone).
__global__ __launch_bounds__(1024) void mine_kernel(
    const float* __restrict__ mine, const int* __restrict__ num_pos,
    const int* __restrict__ nnz, const double* __restrict__ d_msum,
    double* __restrict__ neg_acc)
{
    const int b = blockIdx.x;
    const int t = threadIdx.x;
    const int np = num_pos[b];
    const int k = min(3 * np, PP - 1);
    if (k <= 0) return;

    if (k >= nnz[b]) {                   // common case: select everything nonzero
        if (t == 0) atomicAdd(neg_acc, d_msum[b]);
        return;
    }

    const float* mr = mine + (size_t)b * PP;
    __shared__ unsigned hist[256];
    __shared__ unsigned sh_prefix;
    __shared__ int sh_remaining;
    __shared__ float sred[16];

    unsigned prefix = 0;
    int remaining = k;
    for (int lvl = 0; lvl < 4; ++lvl) {
        const int shift = 24 - lvl * 8;
        if (t < 256) hist[t] = 0;
        __syncthreads();
        for (int p = t; p < PP; p += 1024) {
            const unsigned key = __float_as_uint(mr[p]);
            const bool cand = (lvl == 0) || ((key >> (shift + 8)) == prefix);
            const unsigned long long zb = __ballot(cand && key == 0u);
            if ((t & 63) == 0 && zb) atomicAdd(&hist[0], (unsigned)__popcll(zb));
            if (cand && key != 0u) atomicAdd(&hist[(key >> shift) & 255u], 1u);
        }
        __syncthreads();
        if (t == 0) {
            unsigned c = 0;
            int j = 255;
            for (; j > 0; --j) {
                const unsigned h = hist[j];
                if (c + h >= (unsigned)remaining) break;
                c += h;
            }
            sh_prefix = (prefix << 8) | (unsigned)j;
            sh_remaining = remaining - (int)c;
        }
        __syncthreads();
        prefix = sh_prefix;
        remaining = sh_remaining;
        __syncthreads();
    }

    const unsigned vkey = prefix;
    const float v = __uint_as_float(vkey);
    float sgt = 0.f;
    for (int p = t; p < PP; p += 1024) {
        const float mv = mr[p];
        if (__float_as_uint(mv) > vkey) sgt += mv;
    }
#pragma unroll
    for (int off = 32; off; off >>= 1) sgt += __shfl_down(sgt, off);
    if ((t & 63) == 0) sred[t >> 6] = sgt;
    __syncthreads();
    if (t == 0) {
        float tot = 0.f;
#pragma unroll
        for (int w2 = 0; w2 < 16; ++w2) tot += sred[w2];
        tot += (float)remaining * v;     // boundary-value ties
        atomicAdd(neg_acc, (double)tot);
    }
}

__global__ void finalize_kernel(const double* __restrict__ neg_acc,
                                const double* __restrict__ d_ll,
                                const double* __restrict__ d_ce,
                                const int* __restrict__ num_pos,
                                float* __restrict__ out)
{
    if (threadIdx.x == 0 && blockIdx.x == 0) {
        int N = 0;
        double sll = 0.0, sce = 0.0;
#pragma unroll
        for (int b = 0; b < BB; ++b) { N += num_pos[b]; sll += d_ll[b]; sce += d_ce[b]; }
        const double dN = (double)N;
        out[0] = (float)(sll / dN);                 // LOC_WEIGHT = 1
        out[1] = (float)((sce + neg_acc[0]) / dN);  // CONF_WEIGHT = 1
    }
}

extern "C" void kernel_launch(void* const* d_in, const int* in_sizes, int n_in,
                              void* d_out, int out_size, void* d_ws, size_t ws_size,
                              hipStream_t stream)
{
    const float* locd   = (const float*)d_in[0];
    const float* conf   = (const float*)d_in[1];
    const float* loct   = (const float*)d_in[2];
    const int*   labels = (const int*)d_in[3];
    float* out = (float*)d_out;

    char* ws = (char*)d_ws;
    double* neg_acc = (double*)ws;
    double* d_ll    = (double*)(ws + 8);
    double* d_ce    = (double*)(ws + 264);
    double* d_msum  = (double*)(ws + 520);
    int*    numpos  = (int*)(ws + 776);
    int*    nnzp    = (int*)(ws + 904);
    float*  mine    = (float*)(ws + 2048);

    hipMemsetAsync(d_ws, 0, 2048, stream);   // zero accumulators (graph-safe)

    ce_loc_kernel<<<(BB * PP) / RPB, TPB, 0, stream>>>(conf, labels, locd, loct,
                                                       mine, d_ll, d_ce, d_msum,
                                                       numpos, nnzp);
    mine_kernel<<<BB, 1024, 0, stream>>>(mine, numpos, nnzp, d_msum, neg_acc);
    finalize_kernel<<<1, 64, 0, stream>>>(neg_acc, d_ll, d_ce, numpos, out);
}

// Round 5
// 90.099 us; speedup vs baseline: 2.2006x; 2.2006x over previous
//
#include <hip/hip_runtime.h>

#define BB 32
#define PP 32768
#define CC 81
#define RPB 64                      // rows per tile
#define TPB 256                     // 4 threads per row
#define NT 16                       // tiles per block
#define GRID ((BB * PP) / (RPB * NT))   // 1024 blocks = 4/CU, all co-resident

// ws layout (bytes):
//   0:    double neg_acc
//   8:    double d_ll[32]
//   264:  double d_ce[32]
//   520:  double d_msum[32]
//   776:  int    num_pos[32]
//   904:  int    nnz[32]
//   2048: float  mine[B*P]  (4 MB)

__device__ __forceinline__ float sl1f(float d) {
    float ad = fabsf(d);
    return ad < 1.f ? 0.5f * d * d : ad - 0.5f;
}

#define EXP4(w) { w.x = __expf(w.x); w.y = __expf(w.y); w.z = __expf(w.z); w.w = __expf(w.w); }

__global__ __launch_bounds__(TPB) void ce_loc_kernel(
    const float* __restrict__ conf, const int* __restrict__ labels,
    const float* __restrict__ locd, const float* __restrict__ loct,
    float* __restrict__ mine, double* __restrict__ d_ll, double* __restrict__ d_ce,
    double* __restrict__ d_msum, int* __restrict__ num_pos, int* __restrict__ nnz)
{
    __shared__ float ex[RPB * CC];          // 20736 B
    __shared__ float part[4][5];

    const int t = threadIdx.x;
    const int r = t >> 2, q = t & 3;
    const size_t row0 = (size_t)blockIdx.x * (RPB * NT);
    const int b = blockIdx.x >> 5;          // 32 blocks per batch row

    // prologue: load tile 0 into regs (1296 float4: 5/thread + 16-thread tail)
    float4 v0, v1, v2, v3, v4, vt;
    {
        const float4* s = (const float4*)(conf + row0 * CC);
        v0 = s[t]; v1 = s[t + 256]; v2 = s[t + 512]; v3 = s[t + 768]; v4 = s[t + 1024];
        if (t < 16) vt = s[1280 + t];
    }

    float a_ll = 0.f, a_pce = 0.f, a_pc = 0.f, a_mv = 0.f, a_nz = 0.f;

    for (int it = 0; it < NT; ++it) {
        __syncthreads();                    // previous tile fully consumed
        // exp + deposit current regs to LDS
        float4* dx = (float4*)ex;
        float4 w;
        w = v0; EXP4(w); dx[t]        = w;
        w = v1; EXP4(w); dx[t + 256]  = w;
        w = v2; EXP4(w); dx[t + 512]  = w;
        w = v3; EXP4(w); dx[t + 768]  = w;
        w = v4; EXP4(w); dx[t + 1024] = w;
        if (t < 16) { w = vt; EXP4(w); dx[1280 + t] = w; }

        // issue next tile's loads NOW — in flight across the whole compute phase
        if (it + 1 < NT) {
            const float4* s = (const float4*)(conf + (row0 + (size_t)(it + 1) * RPB) * CC);
            v0 = s[t]; v1 = s[t + 256]; v2 = s[t + 512]; v3 = s[t + 768]; v4 = s[t + 1024];
            if (t < 16) vt = s[1280 + t];
        }
        __syncthreads();                    // ex[] visible

        // ---- all-thread reduce: 4 lanes per row ----
        const size_t gp = row0 + (size_t)it * RPB + r;
        const int lab = labels[gp];
        const bool pos = lab > 0;
        const float* rowp = ex + r * CC;    // banks (17r+q+4c)%32: <=4-way, cheap

        float s0 = 0.f, s1 = 0.f;
#pragma unroll
        for (int c = 0; c < 10; ++c) { s0 += rowp[q + 8 * c]; s1 += rowp[q + 8 * c + 4]; }
        float s = s0 + s1;
        if (q == 0) s += rowp[80];

        // loc smooth-L1: lane q takes component q; index = blockbase + t (coalesced)
        float ll = pos ? sl1f(locd[gp * 4 + q] - loct[gp * 4 + q]) : 0.f;

        s  += __shfl_xor(s, 1);  ll += __shfl_xor(ll, 1);
        s  += __shfl_xor(s, 2);  ll += __shfl_xor(ll, 2);

        if (q == 0) {
            const float exl = rowp[lab];                  // exp(x[label])
            const float ce = __logf(__fdividef(s, exl));  // log(sum) - x[label]
            a_ll += ll;
            float mv = 0.f;
            if (pos) { a_pce += ce; a_pc += 1.f; }
            else {
                mv = fmaxf(ce, 0.f);                      // uint-monotone radix keys
                a_mv += mv;
                a_nz += (mv > 0.f) ? 1.f : 0.f;
            }
            mine[gp] = mv;
        }
    }

    // ---- one reduce + 5 atomics per block ----
#pragma unroll
    for (int off = 32; off; off >>= 1) {
        a_ll  += __shfl_down(a_ll, off);
        a_pce += __shfl_down(a_pce, off);
        a_pc  += __shfl_down(a_pc, off);
        a_mv  += __shfl_down(a_mv, off);
        a_nz  += __shfl_down(a_nz, off);
    }
    const int wv = t >> 6;
    if ((t & 63) == 0) {
        part[wv][0] = a_ll; part[wv][1] = a_pce; part[wv][2] = a_pc;
        part[wv][3] = a_mv; part[wv][4] = a_nz;
    }
    __syncthreads();
    if (t == 0) {
        float x0 = 0, x1 = 0, x2 = 0, x3 = 0, x4 = 0;
#pragma unroll
        for (int i = 0; i < 4; ++i) {
            x0 += part[i][0]; x1 += part[i][1]; x2 += part[i][2];
            x3 += part[i][3]; x4 += part[i][4];
        }
        atomicAdd(&d_ll[b], (double)x0);
        atomicAdd(&d_ce[b], (double)x1);
        atomicAdd(&num_pos[b], (int)x2);
        atomicAdd(&d_msum[b], (double)x3);
        atomicAdd(&nnz[b], (int)x4);
    }
}

// Per-row top-k sum. Fast path: k >= nnz => answer is msum[b]. General inputs
// fall back to radix select on float bits (keys >= 0, uint-monotone).
__global__ __launch_bounds__(1024) void mine_kernel(
    const float* __restrict__ mine, const int* __restrict__ num_pos,
    const int* __restrict__ nnz, const double* __restrict__ d_msum,
    double* __restrict__ neg_acc)
{
    const int b = blockIdx.x;
    const int t = threadIdx.x;
    const int np = num_pos[b];
    const int k = min(3 * np, PP - 1);
    if (k <= 0) return;

    if (k >= nnz[b]) {                   // common case: select everything nonzero
        if (t == 0) atomicAdd(neg_acc, d_msum[b]);
        return;
    }

    const float* mr = mine + (size_t)b * PP;
    __shared__ unsigned hist[256];
    __shared__ unsigned sh_prefix;
    __shared__ int sh_remaining;
    __shared__ float sred[16];

    unsigned prefix = 0;
    int remaining = k;
    for (int lvl = 0; lvl < 4; ++lvl) {
        const int shift = 24 - lvl * 8;
        if (t < 256) hist[t] = 0;
        __syncthreads();
        for (int p = t; p < PP; p += 1024) {
            const unsigned key = __float_as_uint(mr[p]);
            const bool cand = (lvl == 0) || ((key >> (shift + 8)) == prefix);
            const unsigned long long zb = __ballot(cand && key == 0u);
            if ((t & 63) == 0 && zb) atomicAdd(&hist[0], (unsigned)__popcll(zb));
            if (cand && key != 0u) atomicAdd(&hist[(key >> shift) & 255u], 1u);
        }
        __syncthreads();
        if (t == 0) {
            unsigned c = 0;
            int j = 255;
            for (; j > 0; --j) {
                const unsigned h = hist[j];
                if (c + h >= (unsigned)remaining) break;
                c += h;
            }
            sh_prefix = (prefix << 8) | (unsigned)j;
            sh_remaining = remaining - (int)c;
        }
        __syncthreads();
        prefix = sh_prefix;
        remaining = sh_remaining;
        __syncthreads();
    }

    const unsigned vkey = prefix;
    const float v = __uint_as_float(vkey);
    float sgt = 0.f;
    for (int p = t; p < PP; p += 1024) {
        const float mv = mr[p];
        if (__float_as_uint(mv) > vkey) sgt += mv;
    }
#pragma unroll
    for (int off = 32; off; off >>= 1) sgt += __shfl_down(sgt, off);
    if ((t & 63) == 0) sred[t >> 6] = sgt;
    __syncthreads();
    if (t == 0) {
        float tot = 0.f;
#pragma unroll
        for (int w2 = 0; w2 < 16; ++w2) tot += sred[w2];
        tot += (float)remaining * v;     // boundary-value ties
        atomicAdd(neg_acc, (double)tot);
    }
}

__global__ void finalize_kernel(const double* __restrict__ neg_acc,
                                const double* __restrict__ d_ll,
                                const double* __restrict__ d_ce,
                                const int* __restrict__ num_pos,
                                float* __restrict__ out)
{
    if (threadIdx.x == 0 && blockIdx.x == 0) {
        int N = 0;
        double sll = 0.0, sce = 0.0;
#pragma unroll
        for (int b = 0; b < BB; ++b) { N += num_pos[b]; sll += d_ll[b]; sce += d_ce[b]; }
        const double dN = (double)N;
        out[0] = (float)(sll / dN);                 // LOC_WEIGHT = 1
        out[1] = (float)((sce + neg_acc[0]) / dN);  // CONF_WEIGHT = 1
    }
}

extern "C" void kernel_launch(void* const* d_in, const int* in_sizes, int n_in,
                              void* d_out, int out_size, void* d_ws, size_t ws_size,
                              hipStream_t stream)
{
    const float* locd   = (const float*)d_in[0];
    const float* conf   = (const float*)d_in[1];
    const float* loct   = (const float*)d_in[2];
    const int*   labels = (const int*)d_in[3];
    float* out = (float*)d_out;

    char* ws = (char*)d_ws;
    double* neg_acc = (double*)ws;
    double* d_ll    = (double*)(ws + 8);
    double* d_ce    = (double*)(ws + 264);
    double* d_msum  = (double*)(ws + 520);
    int*    numpos  = (int*)(ws + 776);
    int*    nnzp    = (int*)(ws + 904);
    float*  mine    = (float*)(ws + 2048);

    hipMemsetAsync(d_ws, 0, 2048, stream);   // zero accumulators (graph-safe)

    ce_loc_kernel<<<GRID, TPB, 0, stream>>>(conf, labels, locd, loct,
                                            mine, d_ll, d_ce, d_msum,
                                            numpos, nnzp);
    mine_kernel<<<BB, 1024, 0, stream>>>(mine, numpos, nnzp, d_msum, neg_acc);
    finalize_kernel<<<1, 64, 0, stream>>>(neg_acc, d_ll, d_ce, numpos, out);
}